// Round 4
// baseline (110.581 us; speedup 1.0000x reference)
//
#include <hip/hip_runtime.h>

#define B_ 32
#define N_ 1024
#define G_ 2
#define E_ 32
#define M_ (B_*N_)
#define NEG 0.01f
#define QT 64
#define KT 128
#define QSC (1.4426950408889634f/32.0f)   // log2(e)/E folded into Q

using half8  = __attribute__((ext_vector_type(8))) _Float16;
using half4  = __attribute__((ext_vector_type(4))) _Float16;
using floatx4 = __attribute__((ext_vector_type(4))) float;

#if defined(__has_builtin)
#if __has_builtin(__builtin_amdgcn_exp2f)
#define EXP2(x) __builtin_amdgcn_exp2f(x)
#endif
#endif
#ifndef EXP2
#define EXP2(x) exp2f(x)
#endif

// ---------------- Kernel 1: MFMA grouped QKV projection ----------------
// x: (M,64) fp32; w: (192,32) fp32. Outputs fp16: Qh,Kh,Vh (bg,n,e) [Q
// pre-scaled by QSC], Vth (bg,e,n). All global stores coalesced half8 via LDS.
__global__ __launch_bounds__(256) void qkv_kernel(
    const float* __restrict__ x, const float* __restrict__ w, const float* __restrict__ bias,
    _Float16* __restrict__ Qh, _Float16* __restrict__ Kh,
    _Float16* __restrict__ Vh, _Float16* __restrict__ Vth)
{
    __shared__ _Float16 wsh[192*36];
    __shared__ float bsh[192];
    __shared__ _Float16 sQ[64*72], sK[64*72], sV[64*72];  // [r][g*32+e], stride 72
    __shared__ _Float16 vT[64*72];                         // [g*32+e][r], stride 72
    int t = threadIdx.x;
    for (int idx = t; idx < 192*32; idx += 256) {
        int r = idx >> 5, c = idx & 31;
        wsh[r*36 + c] = (_Float16)w[idx];
    }
    if (t < 192) bsh[t] = bias[t];
    __syncthreads();

    int lane = t & 63, wv = t >> 6;
    int L15 = lane & 15, quad = lane >> 4;
    int row0 = blockIdx.x*64 + wv*16;      // wave handles 16 rows
    int b = row0 >> 10, nn0g = (blockIdx.x*64) & 1023;

    // A-frags: A[m=L15][k=quad*4+j] = x[row0+L15][g*32 + kt*16 + quad*4 + j]
    half4 ax[2][2];
    #pragma unroll
    for (int g2 = 0; g2 < 2; g2++)
        #pragma unroll
        for (int kt = 0; kt < 2; kt++) {
            float4 f = *(const float4*)(x + (size_t)(row0+L15)*64 + g2*32 + kt*16 + quad*4);
            half4 h = { (_Float16)f.x, (_Float16)f.y, (_Float16)f.z, (_Float16)f.w };
            ax[g2][kt] = h;
        }

    floatx4 acc[12];
    #pragma unroll
    for (int i = 0; i < 12; i++) acc[i] = (floatx4){0.f,0.f,0.f,0.f};

    #pragma unroll
    for (int g2 = 0; g2 < 2; g2++)
        #pragma unroll
        for (int nt = 0; nt < 6; nt++)
            #pragma unroll
            for (int kt = 0; kt < 2; kt++) {
                half4 bw = *(const half4*)&wsh[(g2*96+nt*16+L15)*36 + kt*16 + quad*4];
                acc[g2*6+nt] = __builtin_amdgcn_mfma_f32_16x16x16f16(ax[g2][kt], bw, acc[g2*6+nt], 0,0,0);
            }

    // D[m=row=quad*4+reg][n=o=nt*16+L15] -> LDS staging
    #pragma unroll
    for (int g2 = 0; g2 < 2; g2++) {
        #pragma unroll
        for (int nt = 0; nt < 6; nt++) {
            float bia = bsh[g2*96 + nt*16 + L15];
            floatx4 a4 = acc[g2*6+nt];
            int e = (nt & 1)*16 + L15;
            int kind = nt >> 1;   // 0:q 1:k 2:v
            int rbase = wv*16 + quad*4;
            if (kind == 0) {
                #pragma unroll
                for (int r = 0; r < 4; r++)
                    sQ[(rbase+r)*72 + g2*32 + e] = (_Float16)((a4[r] + bia)*QSC);
            } else if (kind == 1) {
                #pragma unroll
                for (int r = 0; r < 4; r++)
                    sK[(rbase+r)*72 + g2*32 + e] = (_Float16)(a4[r] + bia);
            } else {
                half4 vv;
                #pragma unroll
                for (int r = 0; r < 4; r++) {
                    float vval = a4[r] + bia;
                    sV[(rbase+r)*72 + g2*32 + e] = (_Float16)vval;
                    vv[r] = (_Float16)vval;
                }
                *(half4*)&vT[(g2*32+e)*72 + rbase] = vv;
            }
        }
    }
    __syncthreads();

    // coalesced half8 write-out
    int r = t >> 2, c8 = t & 3;      // 64 rows x 4 chunks
    #pragma unroll
    for (int g2 = 0; g2 < 2; g2++) {
        size_t gbase = (((size_t)(b*2+g2))*N_ + nn0g + r)*32 + c8*8;
        *(half8*)(Qh + gbase) = *(const half8*)&sQ[r*72 + g2*32 + c8*8];
        *(half8*)(Kh + gbase) = *(const half8*)&sK[r*72 + g2*32 + c8*8];
        *(half8*)(Vh + gbase) = *(const half8*)&sV[r*72 + g2*32 + c8*8];
    }
    // Vth: 64 (g,e) rows x 8 chunks = 512 half8 -> 2 per thread
    #pragma unroll
    for (int it = 0; it < 2; it++) {
        int idx = t + it*256;
        int ge = idx >> 3, c = idx & 7;      // ge = g*32+e
        *(half8*)(Vth + ((size_t)(b*2)*32 + ge)*N_ + nn0g + c*8) = *(const half8*)&vT[ge*72 + c*8];
    }
}

// ---------------- Kernel 2: MFMA attention + MFMA MLP (QT=64) ----------------
struct __align__(16) SmemU {
    union {
        struct { _Float16 Kst[128*40]; _Float16 Vtst[32*136]; } a;  // 18.9 KB
        _Float16 xs[64*72];   // [q][ v(32) | attn(32) ], stride 72
    } u;
    float linv[64];
    float bl1[32], bl10[32], bl11[32];
};

__global__ __launch_bounds__(256, 4) void attn_mlp_kernel(
    const _Float16* __restrict__ Qh, const _Float16* __restrict__ Kh,
    const _Float16* __restrict__ Vh, const _Float16* __restrict__ Vth,
    const float* __restrict__ w_h1,  const float* __restrict__ b_h1,
    const float* __restrict__ w_h10, const float* __restrict__ b_h10,
    const float* __restrict__ w_h11, const float* __restrict__ b_h11,
    float* __restrict__ out)
{
    __shared__ SmemU sm;
    int t = threadIdx.x;
    int bg = blockIdx.x >> 4;
    int qtile = blockIdx.x & 15;
    int b = bg >> 1, g = bg & 1;
    int qbase = qtile * QT;
    size_t bgN = (size_t)bg * N_;

    if (t < 32) {
        sm.bl1[t]  = b_h1[g*32+t];
        sm.bl10[t] = b_h10[g*32+t];
        sm.bl11[t] = b_h11[g*32+t];
    }

    int lane = t & 63;
    int w    = t >> 6;          // wave handles q rows [q0w, q0w+16)
    int L15  = lane & 15;
    int quad = lane >> 4;
    int q0w  = qbase + w*16;

    // Q B-fragment: B[k=e=quad*8+j][n=q=L15]
    half8 bq = *(const half8*)(Qh + (bgN + q0w + L15)*32 + quad*8);

    floatx4 o0 = {0.f,0.f,0.f,0.f}, o1 = o0;
    float lsum = 0.f;

    for (int kt = 0; kt < N_/KT; kt++) {
        __syncthreads();
        #pragma unroll
        for (int it = 0; it < 2; it++) {
            int idx = t + it*256;
            int row = idx >> 2, c = idx & 3;
            half8 kv = *(const half8*)(Kh + (bgN + (size_t)kt*KT + row)*32 + c*8);
            *(half8*)&sm.u.a.Kst[row*40 + c*8] = kv;
        }
        #pragma unroll
        for (int it = 0; it < 2; it++) {
            int idx = t + it*256;
            int ee = idx >> 4, c = idx & 15;
            half8 vv = *(const half8*)(Vth + (size_t)bg*(32*N_) + (size_t)ee*N_ + kt*KT + c*8);
            *(half8*)&sm.u.a.Vtst[ee*136 + c*8] = vv;
        }
        __syncthreads();

        #pragma unroll
        for (int mt = 0; mt < 8; mt++) {
            half8 ak = *(const half8*)&sm.u.a.Kst[(mt*16 + L15)*40 + quad*8];
            floatx4 z = {0.f,0.f,0.f,0.f};
            floatx4 s = __builtin_amdgcn_mfma_f32_16x16x32_f16(ak, bq, z, 0, 0, 0);
            float p0 = EXP2(s.x), p1 = EXP2(s.y), p2 = EXP2(s.z), p3 = EXP2(s.w);
            lsum += (p0+p1)+(p2+p3);
            half4 a0 = { (_Float16)p0, (_Float16)p1, (_Float16)p2, (_Float16)p3 };
            half4 bv0 = *(const half4*)&sm.u.a.Vtst[      L15*136 + mt*16 + quad*4];
            half4 bv1 = *(const half4*)&sm.u.a.Vtst[(16+L15)*136 + mt*16 + quad*4];
            o0 = __builtin_amdgcn_mfma_f32_16x16x16f16(a0, bv0, o0, 0, 0, 0);
            o1 = __builtin_amdgcn_mfma_f32_16x16x16f16(a0, bv1, o1, 0, 0, 0);
        }
    }

    lsum += __shfl_xor(lsum, 16, 64); lsum += __shfl_xor(lsum, 32, 64);
    if (quad == 0) sm.linv[w*16 + L15] = 1.0f / lsum;
    __syncthreads();   // linv visible; all K-loop LDS reads done (union reuse)

    // xs: v part (coalesced fp16 copy) — 64 rows x 4 chunks, 1 per thread
    {
        int row = t >> 2, c = t & 3;
        half8 vv = *(const half8*)(Vh + (bgN + qbase + row)*32 + c*8);
        *(half8*)&sm.u.xs[row*72 + c*8] = vv;
    }
    // attn part: lane holds O[q=w*16+quad*4+r][e=et*16+L15]
    {
        float4 li = *(const float4*)&sm.linv[w*16 + quad*4];
        const floatx4* ofr[2] = { &o0, &o1 };
        #pragma unroll
        for (int et = 0; et < 2; et++) {
            floatx4 ov = *ofr[et];
            sm.u.xs[(w*16+quad*4+0)*72 + 32 + et*16 + L15] = (_Float16)(ov[0]*li.x);
            sm.u.xs[(w*16+quad*4+1)*72 + 32 + et*16 + L15] = (_Float16)(ov[1]*li.y);
            sm.u.xs[(w*16+quad*4+2)*72 + 32 + et*16 + L15] = (_Float16)(ov[2]*li.z);
            sm.u.xs[(w*16+quad*4+3)*72 + 32 + et*16 + L15] = (_Float16)(ov[3]*li.w);
        }
    }
    __syncthreads();

    // weight A-frags: A[m=L15][k=quad*4+j]
    half4 a1f[2][4], a2f[2][2], a3f[2][2];
    #pragma unroll
    for (int mt = 0; mt < 2; mt++) {
        #pragma unroll
        for (int kt = 0; kt < 4; kt++) {
            float4 f = *(const float4*)(w_h1 + (size_t)(g*32+mt*16+L15)*64 + kt*16 + quad*4);
            half4 h = { (_Float16)f.x, (_Float16)f.y, (_Float16)f.z, (_Float16)f.w };
            a1f[mt][kt] = h;
        }
        #pragma unroll
        for (int kt = 0; kt < 2; kt++) {
            float4 f = *(const float4*)(w_h10 + (size_t)(g*32+mt*16+L15)*32 + kt*16 + quad*4);
            half4 h = { (_Float16)f.x, (_Float16)f.y, (_Float16)f.z, (_Float16)f.w };
            a2f[mt][kt] = h;
            float4 f2 = *(const float4*)(w_h11 + (size_t)(g*32+mt*16+L15)*32 + kt*16 + quad*4);
            half4 h2 = { (_Float16)f2.x, (_Float16)f2.y, (_Float16)f2.z, (_Float16)f2.w };
            a3f[mt][kt] = h2;
        }
    }

    // layer 1: D[o][q] over this wave's 16 q rows
    floatx4 d1[2] = { {0.f,0.f,0.f,0.f}, {0.f,0.f,0.f,0.f} };
    #pragma unroll
    for (int kt = 0; kt < 4; kt++) {
        half4 b1 = *(const half4*)&sm.u.xs[(w*16+L15)*72 + kt*16 + quad*4];
        d1[0] = __builtin_amdgcn_mfma_f32_16x16x16f16(a1f[0][kt], b1, d1[0], 0,0,0);
        d1[1] = __builtin_amdgcn_mfma_f32_16x16x16f16(a1f[1][kt], b1, d1[1], 0,0,0);
    }
    half4 h1b[2];
    #pragma unroll
    for (int mt = 0; mt < 2; mt++) {
        float4 bb = *(const float4*)&sm.bl1[mt*16 + quad*4];
        float v0 = d1[mt][0] + bb.x; v0 = (v0>=0.f)?v0:NEG*v0;
        float v1 = d1[mt][1] + bb.y; v1 = (v1>=0.f)?v1:NEG*v1;
        float v2 = d1[mt][2] + bb.z; v2 = (v2>=0.f)?v2:NEG*v2;
        float v3 = d1[mt][3] + bb.w; v3 = (v3>=0.f)?v3:NEG*v3;
        half4 h = { (_Float16)v0, (_Float16)v1, (_Float16)v2, (_Float16)v3 };
        h1b[mt] = h;   // C layout == B layout: in-register chain
    }
    floatx4 d2[2] = { {0.f,0.f,0.f,0.f}, {0.f,0.f,0.f,0.f} };
    #pragma unroll
    for (int mt = 0; mt < 2; mt++)
        #pragma unroll
        for (int kt = 0; kt < 2; kt++)
            d2[mt] = __builtin_amdgcn_mfma_f32_16x16x16f16(a2f[mt][kt], h1b[kt], d2[mt], 0,0,0);
    half4 h2b[2];
    #pragma unroll
    for (int mt = 0; mt < 2; mt++) {
        float4 bb = *(const float4*)&sm.bl10[mt*16 + quad*4];
        float v0 = d2[mt][0] + bb.x; v0 = (v0>=0.f)?v0:NEG*v0;
        float v1 = d2[mt][1] + bb.y; v1 = (v1>=0.f)?v1:NEG*v1;
        float v2 = d2[mt][2] + bb.z; v2 = (v2>=0.f)?v2:NEG*v2;
        float v3 = d2[mt][3] + bb.w; v3 = (v3>=0.f)?v3:NEG*v3;
        half4 h = { (_Float16)v0, (_Float16)v1, (_Float16)v2, (_Float16)v3 };
        h2b[mt] = h;
    }
    floatx4 d3[2] = { {0.f,0.f,0.f,0.f}, {0.f,0.f,0.f,0.f} };
    #pragma unroll
    for (int mt = 0; mt < 2; mt++)
        #pragma unroll
        for (int kt = 0; kt < 2; kt++)
            d3[mt] = __builtin_amdgcn_mfma_f32_16x16x16f16(a3f[mt][kt], h2b[kt], d3[mt], 0,0,0);
    // store: lane holds out[q=L15-row][o=mt*16+quad*4+r] -> float4 per mt
    #pragma unroll
    for (int mt = 0; mt < 2; mt++) {
        float4 bb = *(const float4*)&sm.bl11[mt*16 + quad*4];
        float4 ov;
        ov.x = d3[mt][0] + bb.x; ov.x = (ov.x>=0.f)?ov.x:NEG*ov.x;
        ov.y = d3[mt][1] + bb.y; ov.y = (ov.y>=0.f)?ov.y:NEG*ov.y;
        ov.z = d3[mt][2] + bb.z; ov.z = (ov.z>=0.f)?ov.z:NEG*ov.z;
        ov.w = d3[mt][3] + bb.w; ov.w = (ov.w>=0.f)?ov.w:NEG*ov.w;
        *(float4*)(out + ((size_t)b*N_ + qbase + w*16 + L15)*64 + g*32 + mt*16 + quad*4) = ov;
    }
}

extern "C" void kernel_launch(void* const* d_in, const int* in_sizes, int n_in,
                              void* d_out, int out_size, void* d_ws, size_t ws_size,
                              hipStream_t stream) {
    const float* x_e   = (const float*)d_in[0];
    const float* w_qkv = (const float*)d_in[1];
    const float* b_qkv = (const float*)d_in[2];
    const float* w_h1  = (const float*)d_in[3];
    const float* b_h1  = (const float*)d_in[4];
    const float* w_h10 = (const float*)d_in[5];
    const float* b_h10 = (const float*)d_in[6];
    const float* w_h11 = (const float*)d_in[7];
    const float* b_h11 = (const float*)d_in[8];
    float* out = (float*)d_out;

    const size_t qkv_elems = (size_t)B_*G_*N_*E_;   // 2,097,152
    _Float16* Qh  = (_Float16*)d_ws;
    _Float16* Kh  = Qh + qkv_elems;
    _Float16* Vh  = Kh + qkv_elems;
    _Float16* Vth = Vh + qkv_elems;

    hipLaunchKernelGGL(qkv_kernel, dim3(M_/64), dim3(256), 0, stream,
                       x_e, w_qkv, b_qkv, Qh, Kh, Vh, Vth);
    hipLaunchKernelGGL(attn_mlp_kernel, dim3(B_*G_*(N_/QT)), dim3(256), 0, stream,
                       Qh, Kh, Vh, Vth, w_h1, b_h1, w_h10, b_h10, w_h11, b_h11, out);
}

// Round 5
// 100.137 us; speedup vs baseline: 1.1043x; 1.1043x over previous
//
#include <hip/hip_runtime.h>

#define B_ 32
#define N_ 1024
#define NEG 0.01f
#define QSC (1.4426950408889634f/32.0f)   // log2(e)/E folded into Q

using half8  = __attribute__((ext_vector_type(8))) _Float16;
using half4  = __attribute__((ext_vector_type(4))) _Float16;
using floatx4 = __attribute__((ext_vector_type(4))) float;

#if defined(__has_builtin)
#if __has_builtin(__builtin_amdgcn_exp2f)
#define EXP2(x) __builtin_amdgcn_exp2f(x)
#endif
#endif
#ifndef EXP2
#define EXP2(x) exp2f(x)
#endif

__device__ inline half8 cvt8(float4 a, float4 b) {
    half8 h;
    h[0]=(_Float16)a.x; h[1]=(_Float16)a.y; h[2]=(_Float16)a.z; h[3]=(_Float16)a.w;
    h[4]=(_Float16)b.x; h[5]=(_Float16)b.y; h[6]=(_Float16)b.z; h[7]=(_Float16)b.w;
    return h;
}

// One fused kernel: grouped QKV projection (on the fly) + MFMA flash attention
// + 3-layer grouped MFMA MLP. Block = (bg, qtile of 128 q-rows), 256 threads.
struct __align__(16) Smem {
    _Float16 wsh[96*36];     // Wq/Wk/Wv for this group, padded stride 36
    float    bsh[96];
    _Float16 Kst[128*40];    // K tile [kpos][e], stride 40
    _Float16 Vtst[32*136];   // Vt tile [e][kpos], stride 136
    union {
        _Float16 qs[128*40]; // projected Q tile (dead after bq frags read)
        _Float16 xs[128*72]; // MLP input [q][ v(32) | attn(32) ], stride 72
    } u;
    float linv[128];
    float bl1[32], bl10[32], bl11[32];
};

__global__ __launch_bounds__(256, 2) void fused_kernel(
    const float* __restrict__ x, const float* __restrict__ w_qkv, const float* __restrict__ b_qkv,
    const float* __restrict__ w_h1,  const float* __restrict__ b_h1,
    const float* __restrict__ w_h10, const float* __restrict__ b_h10,
    const float* __restrict__ w_h11, const float* __restrict__ b_h11,
    float* __restrict__ out)
{
    __shared__ Smem sm;
    int t = threadIdx.x;
    int bg = blockIdx.x >> 3;
    int qtile = blockIdx.x & 7;
    int b = bg >> 1, g = bg & 1;
    int qbase = qtile * 128;
    int lane = t & 63, w = t >> 6;
    int L15 = lane & 15, quad = lane >> 4;

    // ---- stage qkv weights (this group only) + biases ----
    for (int idx = t; idx < 96*32; idx += 256) {
        int r = idx >> 5, c = idx & 31;
        sm.wsh[r*36 + c] = (_Float16)w_qkv[(g*96 + r)*32 + c];
    }
    if (t < 96) sm.bsh[t] = b_qkv[g*96 + t];
    if (t < 32) {
        sm.bl1[t]  = b_h1[g*32+t];
        sm.bl10[t] = b_h10[g*32+t];
        sm.bl11[t] = b_h11[g*32+t];
    }
    __syncthreads();

    // ---- weight B-frags (registers): B[k=i=quad*8+j][n=e=et*16+L15] = W[e][i] ----
    half8 bwq[2], bwk[2], bwv[2];
    float bqv[2], bkv[2], bvv[2];
    #pragma unroll
    for (int et = 0; et < 2; et++) {
        bwq[et] = *(const half8*)&sm.wsh[(     et*16 + L15)*36 + quad*8];
        bwk[et] = *(const half8*)&sm.wsh[(32 + et*16 + L15)*36 + quad*8];
        bwv[et] = *(const half8*)&sm.wsh[(64 + et*16 + L15)*36 + quad*8];
        bqv[et] = sm.bsh[     et*16 + L15];
        bkv[et] = sm.bsh[32 + et*16 + L15];
        bvv[et] = sm.bsh[64 + et*16 + L15];
    }

    // ---- project Q for own 32 rows/wave -> qs -> B-frags ----
    {
        floatx4 z = {0.f,0.f,0.f,0.f};
        floatx4 dq[2][2];
        #pragma unroll
        for (int mt = 0; mt < 2; mt++) {
            const float* p = x + ((size_t)b*N_ + qbase + w*32 + mt*16 + L15)*64 + g*32 + quad*8;
            float4 f0 = *(const float4*)p;
            float4 f1 = *(const float4*)(p + 4);
            half8 axq = cvt8(f0, f1);
            dq[mt][0] = __builtin_amdgcn_mfma_f32_16x16x32_f16(axq, bwq[0], z, 0,0,0);
            dq[mt][1] = __builtin_amdgcn_mfma_f32_16x16x32_f16(axq, bwq[1], z, 0,0,0);
        }
        #pragma unroll
        for (int mt = 0; mt < 2; mt++)
            #pragma unroll
            for (int et = 0; et < 2; et++)
                #pragma unroll
                for (int r = 0; r < 4; r++)
                    sm.u.qs[(w*32 + mt*16 + quad*4 + r)*40 + et*16 + L15] =
                        (_Float16)((dq[mt][et][r] + bqv[et])*QSC);
    }
    __syncthreads();
    half8 bq0 = *(const half8*)&sm.u.qs[(w*32 +      L15)*40 + quad*8];
    half8 bq1 = *(const half8*)&sm.u.qs[(w*32 + 16 + L15)*40 + quad*8];

    // ---- prefetch x rows for K/V tile kt=0 ----
    float4 xf0[2], xf1[2];
    #pragma unroll
    for (int mt = 0; mt < 2; mt++) {
        const float* p = x + ((size_t)b*N_ + 0*128 + w*32 + mt*16 + L15)*64 + g*32 + quad*8;
        xf0[mt] = *(const float4*)p;
        xf1[mt] = *(const float4*)(p + 4);
    }

    floatx4 o00 = {0.f,0.f,0.f,0.f}, o01 = o00, o10 = o00, o11 = o00;
    float lsum0 = 0.f, lsum1 = 0.f;

    for (int kt = 0; kt < 8; kt++) {
        // project K/V tile kt from prefetched x (wave covers rows w*32..w*32+31)
        floatx4 z = {0.f,0.f,0.f,0.f};
        floatx4 dK[2][2], dV[2][2];
        #pragma unroll
        for (int mt = 0; mt < 2; mt++) {
            half8 axk = cvt8(xf0[mt], xf1[mt]);
            dK[mt][0] = __builtin_amdgcn_mfma_f32_16x16x32_f16(axk, bwk[0], z, 0,0,0);
            dK[mt][1] = __builtin_amdgcn_mfma_f32_16x16x32_f16(axk, bwk[1], z, 0,0,0);
            dV[mt][0] = __builtin_amdgcn_mfma_f32_16x16x32_f16(axk, bwv[0], z, 0,0,0);
            dV[mt][1] = __builtin_amdgcn_mfma_f32_16x16x32_f16(axk, bwv[1], z, 0,0,0);
        }
        __syncthreads();   // previous tile fully consumed
        #pragma unroll
        for (int mt = 0; mt < 2; mt++) {
            int rb = w*32 + mt*16 + quad*4;
            #pragma unroll
            for (int et = 0; et < 2; et++) {
                half4 vh;
                #pragma unroll
                for (int r = 0; r < 4; r++) {
                    sm.Kst[(rb + r)*40 + et*16 + L15] = (_Float16)(dK[mt][et][r] + bkv[et]);
                    vh[r] = (_Float16)(dV[mt][et][r] + bvv[et]);
                }
                *(half4*)&sm.Vtst[(et*16 + L15)*136 + rb] = vh;
                if (kt == qtile) {   // own rows' V -> MLP input (block-uniform branch)
                    #pragma unroll
                    for (int r = 0; r < 4; r++)
                        sm.u.xs[(rb + r)*72 + et*16 + L15] = vh[r];
                }
            }
        }
        __syncthreads();   // tile ready
        // prefetch x for tile kt+1; latency hidden behind attention compute below
        if (kt < 7) {
            #pragma unroll
            for (int mt = 0; mt < 2; mt++) {
                const float* p = x + ((size_t)b*N_ + (kt+1)*128 + w*32 + mt*16 + L15)*64 + g*32 + quad*8;
                xf0[mt] = *(const float4*)p;
                xf1[mt] = *(const float4*)(p + 4);
            }
        }
        // attention on tile kt
        #pragma unroll
        for (int mt8 = 0; mt8 < 8; mt8++) {
            half8 ak = *(const half8*)&sm.Kst[(mt8*16 + L15)*40 + quad*8];
            floatx4 zz = {0.f,0.f,0.f,0.f};
            floatx4 s0 = __builtin_amdgcn_mfma_f32_16x16x32_f16(ak, bq0, zz, 0,0,0);
            floatx4 s1 = __builtin_amdgcn_mfma_f32_16x16x32_f16(ak, bq1, zz, 0,0,0);
            float p00 = EXP2(s0.x), p01 = EXP2(s0.y), p02 = EXP2(s0.z), p03 = EXP2(s0.w);
            float p10 = EXP2(s1.x), p11 = EXP2(s1.y), p12 = EXP2(s1.z), p13 = EXP2(s1.w);
            lsum0 += (p00+p01)+(p02+p03);
            lsum1 += (p10+p11)+(p12+p13);
            half4 a0 = { (_Float16)p00, (_Float16)p01, (_Float16)p02, (_Float16)p03 };
            half4 a1 = { (_Float16)p10, (_Float16)p11, (_Float16)p12, (_Float16)p13 };
            half4 bv0 = *(const half4*)&sm.Vtst[      L15*136 + mt8*16 + quad*4];
            half4 bv1 = *(const half4*)&sm.Vtst[(16 + L15)*136 + mt8*16 + quad*4];
            o00 = __builtin_amdgcn_mfma_f32_16x16x16f16(a0, bv0, o00, 0,0,0);
            o01 = __builtin_amdgcn_mfma_f32_16x16x16f16(a0, bv1, o01, 0,0,0);
            o10 = __builtin_amdgcn_mfma_f32_16x16x16f16(a1, bv0, o10, 0,0,0);
            o11 = __builtin_amdgcn_mfma_f32_16x16x16f16(a1, bv1, o11, 0,0,0);
        }
    }

    // ---- softmax denominators ----
    lsum0 += __shfl_xor(lsum0, 16, 64); lsum0 += __shfl_xor(lsum0, 32, 64);
    lsum1 += __shfl_xor(lsum1, 16, 64); lsum1 += __shfl_xor(lsum1, 32, 64);
    if (quad == 0) {
        sm.linv[w*32 +      L15] = 1.0f / lsum0;
        sm.linv[w*32 + 16 + L15] = 1.0f / lsum1;
    }
    __syncthreads();

    // ---- attn part of xs: lane holds O[q=w*32+nt*16+quad*4+r][e=et*16+L15] ----
    {
        const floatx4* ofr[2][2] = { {&o00,&o01}, {&o10,&o11} };
        #pragma unroll
        for (int nt = 0; nt < 2; nt++) {
            float4 li = *(const float4*)&sm.linv[w*32 + nt*16 + quad*4];
            #pragma unroll
            for (int et = 0; et < 2; et++) {
                floatx4 ov = *ofr[nt][et];
                sm.u.xs[(w*32+nt*16+quad*4+0)*72 + 32 + et*16 + L15] = (_Float16)(ov[0]*li.x);
                sm.u.xs[(w*32+nt*16+quad*4+1)*72 + 32 + et*16 + L15] = (_Float16)(ov[1]*li.y);
                sm.u.xs[(w*32+nt*16+quad*4+2)*72 + 32 + et*16 + L15] = (_Float16)(ov[2]*li.z);
                sm.u.xs[(w*32+nt*16+quad*4+3)*72 + 32 + et*16 + L15] = (_Float16)(ov[3]*li.w);
            }
        }
    }
    __syncthreads();

    // ---- MLP weight A-frags: A[m=o=mt*16+L15][k=i=quad*4+j] ----
    half4 a1f[2][4], a2f[2][2], a3f[2][2];
    #pragma unroll
    for (int mt = 0; mt < 2; mt++) {
        #pragma unroll
        for (int kt = 0; kt < 4; kt++) {
            float4 f = *(const float4*)(w_h1 + (size_t)(g*32+mt*16+L15)*64 + kt*16 + quad*4);
            half4 h = { (_Float16)f.x, (_Float16)f.y, (_Float16)f.z, (_Float16)f.w };
            a1f[mt][kt] = h;
        }
        #pragma unroll
        for (int kt = 0; kt < 2; kt++) {
            float4 f = *(const float4*)(w_h10 + (size_t)(g*32+mt*16+L15)*32 + kt*16 + quad*4);
            half4 h = { (_Float16)f.x, (_Float16)f.y, (_Float16)f.z, (_Float16)f.w };
            a2f[mt][kt] = h;
            float4 f2 = *(const float4*)(w_h11 + (size_t)(g*32+mt*16+L15)*32 + kt*16 + quad*4);
            half4 h2 = { (_Float16)f2.x, (_Float16)f2.y, (_Float16)f2.z, (_Float16)f2.w };
            a3f[mt][kt] = h2;
        }
    }

    // ---- layer 1: D[o][q] over this wave's 32 q rows ----
    floatx4 d1[2][2];
    #pragma unroll
    for (int mt = 0; mt < 2; mt++)
        #pragma unroll
        for (int nt = 0; nt < 2; nt++) d1[mt][nt] = (floatx4){0.f,0.f,0.f,0.f};
    #pragma unroll
    for (int nt = 0; nt < 2; nt++)
        #pragma unroll
        for (int kt = 0; kt < 4; kt++) {
            half4 b1 = *(const half4*)&sm.u.xs[(w*32+nt*16+L15)*72 + kt*16 + quad*4];
            d1[0][nt] = __builtin_amdgcn_mfma_f32_16x16x16f16(a1f[0][kt], b1, d1[0][nt], 0,0,0);
            d1[1][nt] = __builtin_amdgcn_mfma_f32_16x16x16f16(a1f[1][kt], b1, d1[1][nt], 0,0,0);
        }
    half4 h1b[2][2];   // C layout == next layer's B layout: in-register chain
    #pragma unroll
    for (int mt = 0; mt < 2; mt++) {
        float4 bb = *(const float4*)&sm.bl1[mt*16 + quad*4];
        #pragma unroll
        for (int nt = 0; nt < 2; nt++) {
            float v0 = d1[mt][nt][0] + bb.x; v0 = (v0>=0.f)?v0:NEG*v0;
            float v1 = d1[mt][nt][1] + bb.y; v1 = (v1>=0.f)?v1:NEG*v1;
            float v2 = d1[mt][nt][2] + bb.z; v2 = (v2>=0.f)?v2:NEG*v2;
            float v3 = d1[mt][nt][3] + bb.w; v3 = (v3>=0.f)?v3:NEG*v3;
            half4 h = { (_Float16)v0, (_Float16)v1, (_Float16)v2, (_Float16)v3 };
            h1b[mt][nt] = h;
        }
    }
    floatx4 d2[2][2];
    #pragma unroll
    for (int mt = 0; mt < 2; mt++)
        #pragma unroll
        for (int nt = 0; nt < 2; nt++) d2[mt][nt] = (floatx4){0.f,0.f,0.f,0.f};
    #pragma unroll
    for (int mt = 0; mt < 2; mt++)
        #pragma unroll
        for (int nt = 0; nt < 2; nt++)
            #pragma unroll
            for (int kt = 0; kt < 2; kt++)
                d2[mt][nt] = __builtin_amdgcn_mfma_f32_16x16x16f16(a2f[mt][kt], h1b[kt][nt], d2[mt][nt], 0,0,0);
    half4 h2b[2][2];
    #pragma unroll
    for (int mt = 0; mt < 2; mt++) {
        float4 bb = *(const float4*)&sm.bl10[mt*16 + quad*4];
        #pragma unroll
        for (int nt = 0; nt < 2; nt++) {
            float v0 = d2[mt][nt][0] + bb.x; v0 = (v0>=0.f)?v0:NEG*v0;
            float v1 = d2[mt][nt][1] + bb.y; v1 = (v1>=0.f)?v1:NEG*v1;
            float v2 = d2[mt][nt][2] + bb.z; v2 = (v2>=0.f)?v2:NEG*v2;
            float v3 = d2[mt][nt][3] + bb.w; v3 = (v3>=0.f)?v3:NEG*v3;
            half4 h = { (_Float16)v0, (_Float16)v1, (_Float16)v2, (_Float16)v3 };
            h2b[mt][nt] = h;
        }
    }
    floatx4 d3[2][2];
    #pragma unroll
    for (int mt = 0; mt < 2; mt++)
        #pragma unroll
        for (int nt = 0; nt < 2; nt++) d3[mt][nt] = (floatx4){0.f,0.f,0.f,0.f};
    #pragma unroll
    for (int mt = 0; mt < 2; mt++)
        #pragma unroll
        for (int nt = 0; nt < 2; nt++)
            #pragma unroll
            for (int kt = 0; kt < 2; kt++)
                d3[mt][nt] = __builtin_amdgcn_mfma_f32_16x16x16f16(a3f[mt][kt], h2b[kt][nt], d3[mt][nt], 0,0,0);
    // store: lane holds out[q=qbase+w*32+nt*16+L15][o=mt*16+quad*4+r] -> float4
    #pragma unroll
    for (int mt = 0; mt < 2; mt++) {
        float4 bb = *(const float4*)&sm.bl11[mt*16 + quad*4];
        #pragma unroll
        for (int nt = 0; nt < 2; nt++) {
            float4 ov;
            ov.x = d3[mt][nt][0] + bb.x; ov.x = (ov.x>=0.f)?ov.x:NEG*ov.x;
            ov.y = d3[mt][nt][1] + bb.y; ov.y = (ov.y>=0.f)?ov.y:NEG*ov.y;
            ov.z = d3[mt][nt][2] + bb.z; ov.z = (ov.z>=0.f)?ov.z:NEG*ov.z;
            ov.w = d3[mt][nt][3] + bb.w; ov.w = (ov.w>=0.f)?ov.w:NEG*ov.w;
            *(float4*)(out + ((size_t)b*N_ + qbase + w*32 + nt*16 + L15)*64 + g*32 + mt*16 + quad*4) = ov;
        }
    }
}

extern "C" void kernel_launch(void* const* d_in, const int* in_sizes, int n_in,
                              void* d_out, int out_size, void* d_ws, size_t ws_size,
                              hipStream_t stream) {
    const float* x_e   = (const float*)d_in[0];
    const float* w_qkv = (const float*)d_in[1];
    const float* b_qkv = (const float*)d_in[2];
    const float* w_h1  = (const float*)d_in[3];
    const float* b_h1  = (const float*)d_in[4];
    const float* w_h10 = (const float*)d_in[5];
    const float* b_h10 = (const float*)d_in[6];
    const float* w_h11 = (const float*)d_in[7];
    const float* b_h11 = (const float*)d_in[8];
    float* out = (float*)d_out;

    hipLaunchKernelGGL(fused_kernel, dim3(B_*2*8), dim3(256), 0, stream,
                       x_e, w_qkv, b_qkv, w_h1, b_h1, w_h10, b_h10, w_h11, b_h11, out);
}

// Round 7
// 98.568 us; speedup vs baseline: 1.1219x; 1.0159x over previous
//
#include <hip/hip_runtime.h>

#define B_ 32
#define N_ 1024
#define NEG 0.01f
#define QSC (1.4426950408889634f/32.0f)   // log2(e)/E folded into staged Wq/bq

using half8  = __attribute__((ext_vector_type(8))) _Float16;
using half4  = __attribute__((ext_vector_type(4))) _Float16;
using half2  = __attribute__((ext_vector_type(2))) _Float16;
using fp16x2 = __attribute__((ext_vector_type(2))) __fp16;
using floatx4 = __attribute__((ext_vector_type(4))) float;

#if defined(__has_builtin)
#if __has_builtin(__builtin_amdgcn_exp2f)
#define EXP2(x) __builtin_amdgcn_exp2f(x)
#endif
#endif
#ifndef EXP2
#define EXP2(x) exp2f(x)
#endif

__device__ inline half2 pkcvt(float a, float b) {
    fp16x2 r = __builtin_amdgcn_cvt_pkrtz(a, b);
    return __builtin_bit_cast(half2, r);
}

__device__ inline half8 cvt8(float4 a, float4 b) {
    half2 p0 = pkcvt(a.x, a.y);
    half2 p1 = pkcvt(a.z, a.w);
    half2 p2 = pkcvt(b.x, b.y);
    half2 p3 = pkcvt(b.z, b.w);
    half8 h = { p0[0],p0[1], p1[0],p1[1], p2[0],p2[1], p3[0],p3[1] };
    return h;
}

// One fused kernel: on-the-fly grouped QKV projection + MFMA flash attention
// + 3-layer grouped MFMA MLP. Block = (bg, qtile of 128 q rows), 256 threads.
// K/V tiles double-buffered in LDS: ONE barrier per K-tile.
struct __align__(16) Smem {
    _Float16 wsh[96*36];       // Wq(pre-scaled)/Wk/Wv for this group, stride 36
    float    bsh[96];
    _Float16 Kst[2][128*40];   // ping-pong K tile [kpos][e]
    _Float16 Vtst[2][32*136];  // ping-pong Vt tile [e][kpos]
    union {
        _Float16 qs[128*40];   // projected Q tile (dead after bq frags read)
        _Float16 xs[128*72];   // MLP input [q][ v(32) | attn(32) ]
    } u;
    float linv[128];
    float bl1[32], bl10[32], bl11[32];
};

__global__ __launch_bounds__(256, 2) void fused_kernel(
    const float* __restrict__ x, const float* __restrict__ w_qkv, const float* __restrict__ b_qkv,
    const float* __restrict__ w_h1,  const float* __restrict__ b_h1,
    const float* __restrict__ w_h10, const float* __restrict__ b_h10,
    const float* __restrict__ w_h11, const float* __restrict__ b_h11,
    float* __restrict__ out)
{
    __shared__ Smem sm;
    int t = threadIdx.x;
    int bg = blockIdx.x >> 3;
    int qtile = blockIdx.x & 7;
    int b = bg >> 1, g = bg & 1;
    int qbase = qtile * 128;
    int lane = t & 63, w = t >> 6;
    int L15 = lane & 15, quad = lane >> 4;

    // ---- stage qkv weights (Q rows pre-scaled by QSC) + biases ----
    for (int idx = t; idx < 96*32; idx += 256) {
        int r = idx >> 5, c = idx & 31;
        float wv = w_qkv[(g*96 + r)*32 + c];
        sm.wsh[r*36 + c] = (_Float16)(r < 32 ? wv*QSC : wv);
    }
    if (t < 96) sm.bsh[t] = b_qkv[g*96 + t];
    if (t < 32) {
        sm.bl1[t]  = b_h1[g*32+t];
        sm.bl10[t] = b_h10[g*32+t];
        sm.bl11[t] = b_h11[g*32+t];
    }
    __syncthreads();

    // ---- weight B-frags: B[k=i=quad*8+j][n=e=et*16+L15] = W[e][i]; bias C-seeds ----
    half8 bwq[2], bwk[2], bwv[2];
    floatx4 cq[2], ck[2], cv[2];
    #pragma unroll
    for (int et = 0; et < 2; et++) {
        bwq[et] = *(const half8*)&sm.wsh[(     et*16 + L15)*36 + quad*8];
        bwk[et] = *(const half8*)&sm.wsh[(32 + et*16 + L15)*36 + quad*8];
        bwv[et] = *(const half8*)&sm.wsh[(64 + et*16 + L15)*36 + quad*8];
        float bq = sm.bsh[     et*16 + L15] * QSC;
        float bk = sm.bsh[32 + et*16 + L15];
        float bv = sm.bsh[64 + et*16 + L15];
        cq[et] = (floatx4){bq,bq,bq,bq};
        ck[et] = (floatx4){bk,bk,bk,bk};
        cv[et] = (floatx4){bv,bv,bv,bv};
    }

    // ---- project Q for own 32 rows/wave -> qs ----
    {
        floatx4 dq[2][2];
        #pragma unroll
        for (int mt = 0; mt < 2; mt++) {
            const float* p = x + ((size_t)b*N_ + qbase + w*32 + mt*16 + L15)*64 + g*32 + quad*8;
            half8 axq = cvt8(*(const float4*)p, *(const float4*)(p + 4));
            dq[mt][0] = __builtin_amdgcn_mfma_f32_16x16x32_f16(axq, bwq[0], cq[0], 0,0,0);
            dq[mt][1] = __builtin_amdgcn_mfma_f32_16x16x32_f16(axq, bwq[1], cq[1], 0,0,0);
        }
        #pragma unroll
        for (int mt = 0; mt < 2; mt++)
            #pragma unroll
            for (int et = 0; et < 2; et++)
                #pragma unroll
                for (int r = 0; r < 4; r++)
                    sm.u.qs[(w*32 + mt*16 + quad*4 + r)*40 + et*16 + L15] =
                        (_Float16)dq[mt][et][r];
    }
    __syncthreads();
    half8 bq0 = *(const half8*)&sm.u.qs[(w*32 +      L15)*40 + quad*8];
    half8 bq1 = *(const half8*)&sm.u.qs[(w*32 + 16 + L15)*40 + quad*8];

    float4 xf0[2], xf1[2];
    auto prefetch = [&](int tile) {
        #pragma unroll
        for (int mt = 0; mt < 2; mt++) {
            const float* p = x + ((size_t)b*N_ + tile*128 + w*32 + mt*16 + L15)*64 + g*32 + quad*8;
            xf0[mt] = *(const float4*)p;
            xf1[mt] = *(const float4*)(p + 4);
        }
    };
    auto proj_tile = [&](int tile, int buf) {
        floatx4 dK[2][2], dV[2][2];
        #pragma unroll
        for (int mt = 0; mt < 2; mt++) {
            half8 axk = cvt8(xf0[mt], xf1[mt]);
            dK[mt][0] = __builtin_amdgcn_mfma_f32_16x16x32_f16(axk, bwk[0], ck[0], 0,0,0);
            dK[mt][1] = __builtin_amdgcn_mfma_f32_16x16x32_f16(axk, bwk[1], ck[1], 0,0,0);
            dV[mt][0] = __builtin_amdgcn_mfma_f32_16x16x32_f16(axk, bwv[0], cv[0], 0,0,0);
            dV[mt][1] = __builtin_amdgcn_mfma_f32_16x16x32_f16(axk, bwv[1], cv[1], 0,0,0);
        }
        #pragma unroll
        for (int mt = 0; mt < 2; mt++) {
            int rb = w*32 + mt*16 + quad*4;
            #pragma unroll
            for (int et = 0; et < 2; et++) {
                half2 k01 = pkcvt(dK[mt][et][0], dK[mt][et][1]);
                half2 k23 = pkcvt(dK[mt][et][2], dK[mt][et][3]);
                half2 v01 = pkcvt(dV[mt][et][0], dV[mt][et][1]);
                half2 v23 = pkcvt(dV[mt][et][2], dV[mt][et][3]);
                half4 vh = { v01[0], v01[1], v23[0], v23[1] };
                sm.Kst[buf][(rb+0)*40 + et*16 + L15] = k01[0];
                sm.Kst[buf][(rb+1)*40 + et*16 + L15] = k01[1];
                sm.Kst[buf][(rb+2)*40 + et*16 + L15] = k23[0];
                sm.Kst[buf][(rb+3)*40 + et*16 + L15] = k23[1];
                *(half4*)&sm.Vtst[buf][(et*16 + L15)*136 + rb] = vh;
                if (tile == qtile) {   // own rows' V -> MLP input (uniform branch)
                    #pragma unroll
                    for (int r = 0; r < 4; r++)
                        sm.u.xs[(rb + r)*72 + et*16 + L15] = vh[r];
                }
            }
        }
    };

    // ---- prologue: tile 0 ----
    prefetch(0);
    proj_tile(0, 0);
    __syncthreads();

    floatx4 o00 = {0.f,0.f,0.f,0.f}, o01 = o00, o10 = o00, o11 = o00;
    float lsum0 = 0.f, lsum1 = 0.f;

    for (int kt = 0; kt < 8; kt++) {
        int cur = kt & 1;
        if (kt < 7) prefetch(kt + 1);
        // attention on tile kt (buf cur) — hides prefetch latency
        #pragma unroll
        for (int mt8 = 0; mt8 < 8; mt8++) {
            half8 ak = *(const half8*)&sm.Kst[cur][(mt8*16 + L15)*40 + quad*8];
            floatx4 zz = {0.f,0.f,0.f,0.f};
            floatx4 s0 = __builtin_amdgcn_mfma_f32_16x16x32_f16(ak, bq0, zz, 0,0,0);
            floatx4 s1 = __builtin_amdgcn_mfma_f32_16x16x32_f16(ak, bq1, zz, 0,0,0);
            float p00 = EXP2(s0.x), p01 = EXP2(s0.y), p02 = EXP2(s0.z), p03 = EXP2(s0.w);
            float p10 = EXP2(s1.x), p11 = EXP2(s1.y), p12 = EXP2(s1.z), p13 = EXP2(s1.w);
            lsum0 += (p00+p01)+(p02+p03);
            lsum1 += (p10+p11)+(p12+p13);
            half2 pa = pkcvt(p00, p01);
            half2 pb = pkcvt(p02, p03);
            half2 pc = pkcvt(p10, p11);
            half2 pd = pkcvt(p12, p13);
            half4 a0 = { pa[0], pa[1], pb[0], pb[1] };
            half4 a1 = { pc[0], pc[1], pd[0], pd[1] };
            half4 bv0 = *(const half4*)&sm.Vtst[cur][      L15*136 + mt8*16 + quad*4];
            half4 bv1 = *(const half4*)&sm.Vtst[cur][(16 + L15)*136 + mt8*16 + quad*4];
            o00 = __builtin_amdgcn_mfma_f32_16x16x16f16(a0, bv0, o00, 0,0,0);
            o01 = __builtin_amdgcn_mfma_f32_16x16x16f16(a0, bv1, o01, 0,0,0);
            o10 = __builtin_amdgcn_mfma_f32_16x16x16f16(a1, bv0, o10, 0,0,0);
            o11 = __builtin_amdgcn_mfma_f32_16x16x16f16(a1, bv1, o11, 0,0,0);
        }
        // project tile kt+1 into the other buffer (no wait on attend reads)
        if (kt < 7) proj_tile(kt + 1, 1 - cur);
        __syncthreads();
    }

    // ---- softmax denominators ----
    lsum0 += __shfl_xor(lsum0, 16, 64); lsum0 += __shfl_xor(lsum0, 32, 64);
    lsum1 += __shfl_xor(lsum1, 16, 64); lsum1 += __shfl_xor(lsum1, 32, 64);
    if (quad == 0) {
        sm.linv[w*32 +      L15] = 1.0f / lsum0;
        sm.linv[w*32 + 16 + L15] = 1.0f / lsum1;
    }
    __syncthreads();

    // ---- attn part of xs: lane holds O[q=w*32+nt*16+quad*4+r][e=et*16+L15] ----
    {
        const floatx4* ofr[2][2] = { {&o00,&o01}, {&o10,&o11} };
        #pragma unroll
        for (int nt = 0; nt < 2; nt++) {
            float4 li = *(const float4*)&sm.linv[w*32 + nt*16 + quad*4];
            #pragma unroll
            for (int et = 0; et < 2; et++) {
                floatx4 ov = *ofr[nt][et];
                sm.u.xs[(w*32+nt*16+quad*4+0)*72 + 32 + et*16 + L15] = (_Float16)(ov[0]*li.x);
                sm.u.xs[(w*32+nt*16+quad*4+1)*72 + 32 + et*16 + L15] = (_Float16)(ov[1]*li.y);
                sm.u.xs[(w*32+nt*16+quad*4+2)*72 + 32 + et*16 + L15] = (_Float16)(ov[2]*li.z);
                sm.u.xs[(w*32+nt*16+quad*4+3)*72 + 32 + et*16 + L15] = (_Float16)(ov[3]*li.w);
            }
        }
    }
    __syncthreads();

    // ---- MLP weight A-frags: A[m=o=mt*16+L15][k=i=quad*4+j] ----
    half4 a1f[2][4], a2f[2][2], a3f[2][2];
    #pragma unroll
    for (int mt = 0; mt < 2; mt++) {
        #pragma unroll
        for (int kt = 0; kt < 4; kt++) {
            float4 f = *(const float4*)(w_h1 + (size_t)(g*32+mt*16+L15)*64 + kt*16 + quad*4);
            half2 ha = pkcvt(f.x, f.y);
            half2 hb = pkcvt(f.z, f.w);
            half4 h = { ha[0], ha[1], hb[0], hb[1] };
            a1f[mt][kt] = h;
        }
        #pragma unroll
        for (int kt = 0; kt < 2; kt++) {
            float4 f = *(const float4*)(w_h10 + (size_t)(g*32+mt*16+L15)*32 + kt*16 + quad*4);
            half2 ha = pkcvt(f.x, f.y);
            half2 hb = pkcvt(f.z, f.w);
            half4 h = { ha[0], ha[1], hb[0], hb[1] };
            a2f[mt][kt] = h;
            float4 f2 = *(const float4*)(w_h11 + (size_t)(g*32+mt*16+L15)*32 + kt*16 + quad*4);
            half2 hc = pkcvt(f2.x, f2.y);
            half2 hd = pkcvt(f2.z, f2.w);
            half4 h2 = { hc[0], hc[1], hd[0], hd[1] };
            a3f[mt][kt] = h2;
        }
    }

    // ---- layer 1 (bias-seeded): D[o][q] over this wave's 32 q rows ----
    floatx4 d1[2][2];
    #pragma unroll
    for (int mt = 0; mt < 2; mt++) {
        float4 bb = *(const float4*)&sm.bl1[mt*16 + quad*4];
        floatx4 seed = { bb.x, bb.y, bb.z, bb.w };
        d1[mt][0] = seed; d1[mt][1] = seed;
    }
    #pragma unroll
    for (int nt = 0; nt < 2; nt++)
        #pragma unroll
        for (int kt = 0; kt < 4; kt++) {
            half4 b1 = *(const half4*)&sm.u.xs[(w*32+nt*16+L15)*72 + kt*16 + quad*4];
            d1[0][nt] = __builtin_amdgcn_mfma_f32_16x16x16f16(a1f[0][kt], b1, d1[0][nt], 0,0,0);
            d1[1][nt] = __builtin_amdgcn_mfma_f32_16x16x16f16(a1f[1][kt], b1, d1[1][nt], 0,0,0);
        }
    half4 h1b[2][2];   // C layout == next layer's B layout: in-register chain
    #pragma unroll
    for (int mt = 0; mt < 2; mt++)
        #pragma unroll
        for (int nt = 0; nt < 2; nt++) {
            float v0 = d1[mt][nt][0]; v0 = (v0>=0.f)?v0:NEG*v0;
            float v1 = d1[mt][nt][1]; v1 = (v1>=0.f)?v1:NEG*v1;
            float v2 = d1[mt][nt][2]; v2 = (v2>=0.f)?v2:NEG*v2;
            float v3 = d1[mt][nt][3]; v3 = (v3>=0.f)?v3:NEG*v3;
            half2 ha = pkcvt(v0, v1);
            half2 hb = pkcvt(v2, v3);
            half4 h = { ha[0], ha[1], hb[0], hb[1] };
            h1b[mt][nt] = h;
        }
    floatx4 d2[2][2];
    #pragma unroll
    for (int mt = 0; mt < 2; mt++) {
        float4 bb = *(const float4*)&sm.bl10[mt*16 + quad*4];
        floatx4 seed = { bb.x, bb.y, bb.z, bb.w };
        d2[mt][0] = seed; d2[mt][1] = seed;
    }
    #pragma unroll
    for (int mt = 0; mt < 2; mt++)
        #pragma unroll
        for (int nt = 0; nt < 2; nt++)
            #pragma unroll
            for (int kt = 0; kt < 2; kt++)
                d2[mt][nt] = __builtin_amdgcn_mfma_f32_16x16x16f16(a2f[mt][kt], h1b[kt][nt], d2[mt][nt], 0,0,0);
    half4 h2b[2][2];
    #pragma unroll
    for (int mt = 0; mt < 2; mt++)
        #pragma unroll
        for (int nt = 0; nt < 2; nt++) {
            float v0 = d2[mt][nt][0]; v0 = (v0>=0.f)?v0:NEG*v0;
            float v1 = d2[mt][nt][1]; v1 = (v1>=0.f)?v1:NEG*v1;
            float v2 = d2[mt][nt][2]; v2 = (v2>=0.f)?v2:NEG*v2;
            float v3 = d2[mt][nt][3]; v3 = (v3>=0.f)?v3:NEG*v3;
            half2 ha = pkcvt(v0, v1);
            half2 hb = pkcvt(v2, v3);
            half4 h = { ha[0], ha[1], hb[0], hb[1] };
            h2b[mt][nt] = h;
        }
    floatx4 d3[2][2];
    #pragma unroll
    for (int mt = 0; mt < 2; mt++) {
        float4 bb = *(const float4*)&sm.bl11[mt*16 + quad*4];
        floatx4 seed = { bb.x, bb.y, bb.z, bb.w };
        d3[mt][0] = seed; d3[mt][1] = seed;
    }
    #pragma unroll
    for (int mt = 0; mt < 2; mt++)
        #pragma unroll
        for (int nt = 0; nt < 2; nt++)
            #pragma unroll
            for (int kt = 0; kt < 2; kt++)
                d3[mt][nt] = __builtin_amdgcn_mfma_f32_16x16x16f16(a3f[mt][kt], h2b[kt][nt], d3[mt][nt], 0,0,0);
    // store: lane holds out[q=qbase+w*32+nt*16+L15][o=mt*16+quad*4+r] -> float4
    #pragma unroll
    for (int mt = 0; mt < 2; mt++)
        #pragma unroll
        for (int nt = 0; nt < 2; nt++) {
            float4 ov;
            ov.x = d3[mt][nt][0]; ov.x = (ov.x>=0.f)?ov.x:NEG*ov.x;
            ov.y = d3[mt][nt][1]; ov.y = (ov.y>=0.f)?ov.y:NEG*ov.y;
            ov.z = d3[mt][nt][2]; ov.z = (ov.z>=0.f)?ov.z:NEG*ov.z;
            ov.w = d3[mt][nt][3]; ov.w = (ov.w>=0.f)?ov.w:NEG*ov.w;
            *(float4*)(out + ((size_t)b*N_ + qbase + w*32 + nt*16 + L15)*64 + g*32 + mt*16 + quad*4) = ov;
        }
}

extern "C" void kernel_launch(void* const* d_in, const int* in_sizes, int n_in,
                              void* d_out, int out_size, void* d_ws, size_t ws_size,
                              hipStream_t stream) {
    const float* x_e   = (const float*)d_in[0];
    const float* w_qkv = (const float*)d_in[1];
    const float* b_qkv = (const float*)d_in[2];
    const float* w_h1  = (const float*)d_in[3];
    const float* b_h1  = (const float*)d_in[4];
    const float* w_h10 = (const float*)d_in[5];
    const float* b_h10 = (const float*)d_in[6];
    const float* w_h11 = (const float*)d_in[7];
    const float* b_h11 = (const float*)d_in[8];
    float* out = (float*)d_out;

    hipLaunchKernelGGL(fused_kernel, dim3(B_*2*8), dim3(256), 0, stream,
                       x_e, w_qkv, b_qkv, w_h1, b_h1, w_h10, b_h10, w_h11, b_h11, out);
}